// Round 12
// baseline (1081.224 us; speedup 1.0000x reference)
//
#include <hip/hip_runtime.h>

// BendingEnergy: fused 19-point stencil + per-batch mean, LDS x-march v8.
// v7 dataflow (each LDS row read ONCE per x-march: center row serves
// XP->C->XM->X2M depth-4, y+-1 rows serve DPP->YP->DMP depth-3; 20
// units/thread-step; 4-slot circular buffer) but rotation by RING-RENAMING:
// 12-phase unrolled groups (12 % 4 == 0, 12 % 3 == 0 -> ring & slot indices
// are pure functions of the phase), template<int P> steps, constexpr indices
// only, no pointers into locals -> SROA promotes rings with per-element
// liveness and ZERO rotation movs (v7 paid 96 v_mov/step for shifts).

typedef float F4 __attribute__((ext_vector_type(4)));

#define DIM 160
#define SX (DIM * DIM * 3)          // 76800
#define SY (DIM * 3)                // 480
#define FSZ ((long long)DIM * SX)
#define TOT (4LL * FSZ)

#define ROWS 20                     // staged y rows per slab (16 out + 4 halo)
#define ROWU 37                     // 16B units per row (36 used + 1 pad)
#define USED_U (ROWS * ROWU)        // 740
#define SLICE_U 744                 // padded to mult of 8
#define SLICE_F (SLICE_U * 4)       // 2976 floats
#define SLOTS 4
#define STEPS 26
#define NSEG 6
#define NMS 4                       // m segments (128 output floats each)
#define NYT 10                      // y tiles (16 rows each)
#define NBLK (4 * NSEG * NMS * NYT) // 960
#define CPX (NBLK / 8)              // 120

#define CB(a, i) a[(i) >> 2][(i) & 3]

struct Ctx {
    const float* f;
    const float* fbase;
    const float* fend;
    long long choff0, choff1, choff2;
    bool ch2ok;
    int tid;
};

__device__ __forceinline__ void stage_slab(const Ctx& c, float* lds,
                                           int slab, int slot) {
    long long sb = (long long)slab * SX;
    long long offs[3] = {c.choff0, c.choff1, c.choff2};
#pragma unroll
    for (int it = 0; it < 3; ++it) {
        if (it < 2 || c.ch2ok) {
            const float* gp = c.fbase + (sb + offs[it]);
            gp = gp < c.f ? c.f : gp;        // clamp buffer ends (masked data)
            gp = gp > c.fend ? c.fend : gp;
            __builtin_amdgcn_global_load_lds(
                (const __attribute__((address_space(1))) unsigned int*)gp,
                (__attribute__((address_space(3))) unsigned int*)
                    ((__attribute__((address_space(3))) float*)lds
                     + slot * SLICE_F + 4 * (it * 256 + c.tid)),
                16, 0, 0);
        }
    }
}

__device__ __forceinline__ F4 LDS4(const float* base, int unit) {
    return *reinterpret_cast<const F4*>(base + 4 * unit);
}

// One x-step at compile-time phase P (P == s mod 12; rings period 4 and 3,
// slots period 4 -> all indices constexpr).
template <int P>
__device__ __forceinline__ void do_step(const Ctx& c, float* lds, int x,
                                        int rc, int jlo, int jhi, float& e,
                                        F4 (&CF)[4][6], F4 (&PF)[3][4],
                                        F4 (&QF)[3][4], bool do_stage) {
    if (do_stage) stage_slab(c, lds, x + 3, (P + 1) & 3);

    const float* Lx  = lds + ((P + 2) & 3) * SLICE_F;   // slab x
    const float* Lx1 = lds + ((P + 3) & 3) * SLICE_F;   // slab x+1
    const float* Lx2 = lds + ((P) & 3) * SLICE_F;       // slab x+2

    constexpr int A0 = P & 3;           // fresh center set   (slab x+1: XP)
    constexpr int A1 = (P + 3) & 3;     // written at P-1     (slab x:   C)
    constexpr int A2 = (P + 2) & 3;     // written at P-2     (slab x-1: XM)
    constexpr int A3 = (P + 1) & 3;     // written at P-3     (slab x-2: X2M)
    constexpr int B0 = P % 3;           // fresh y+-1 sets    (slab x+1: DPP/DMM')
    constexpr int B1 = (P + 2) % 3;     // written at P-1     (slab x:   YP/YM)
    constexpr int B2 = (P + 1) % 3;     // written at P-2     (slab x-1: DMP/DMM)

    // fresh reads: 14 units (center 6, y+1 4, y-1 4), all from slab x+1
#pragma unroll
    for (int i = 0; i < 6; ++i) CF[A0][i] = LDS4(Lx1, rc + i);
#pragma unroll
    for (int i = 0; i < 4; ++i) {
        PF[B0][i] = LDS4(Lx1, rc + ROWU + 1 + i);
        QF[B0][i] = LDS4(Lx1, rc - ROWU + 1 + i);
    }
    // direct reads: 6 units
    F4 X2Pa[2], Y2Pa[2], Y2Ma[2];
    X2Pa[0] = LDS4(Lx2, rc + 2);            X2Pa[1] = LDS4(Lx2, rc + 3);
    Y2Pa[0] = LDS4(Lx, rc + 2 * ROWU + 2);  Y2Pa[1] = LDS4(Lx, rc + 2 * ROWU + 3);
    Y2Ma[0] = LDS4(Lx, rc - 2 * ROWU + 2);  Y2Ma[1] = LDS4(Lx, rc - 2 * ROWU + 3);

    // element maps (full 6-unit layout, floats m0-8+k):
    // C = CF[A1]: k = j+8 (ctr), j+2 / j+14 (dzz)
    // XP = CF[A0], XM = CF[A2]: k = j+5, j+11
    // X2M = CF[A3]: k = j+8
    // p/q layout (floats m0-4+i): DPP/DMM' = [B0] i=j+4; YP/YM = [B1] i=j+1,
    // j+7; DMP/DMM = [B2] i=j+4
#pragma unroll
    for (int j = 0; j < 8; ++j) {
        float ctr2 = 2.0f * CB(CF[A1], j + 8);
        float dxx = (CB(X2Pa, j) + CB(CF[A3], j + 8)) - ctr2;
        float dyy = (CB(Y2Pa, j) + CB(Y2Ma, j)) - ctr2;
        float dzz = (CB(CF[A1], j + 2) + CB(CF[A1], j + 14)) - ctr2;
        float dxy = (CB(PF[B0], j + 4) - CB(PF[B2], j + 4))
                  - (CB(QF[B0], j + 4) - CB(QF[B2], j + 4));
        float dxz = (CB(CF[A0], j + 11) - CB(CF[A2], j + 11))
                  - (CB(CF[A0], j + 5) - CB(CF[A2], j + 5));
        float dyz = (CB(PF[B1], j + 7) - CB(QF[B1], j + 7))
                  - (CB(PF[B1], j + 1) - CB(QF[B1], j + 1));
        float dd = dxx * dxx + dyy * dyy + dzz * dzz;
        float dc = dxy * dxy + dxz * dxz + dyz * dyz;
        float msk = (j >= jlo && j < jhi) ? 1.0f : 0.0f;
        e += msk * (dd + 2.0f * dc);
    }

    __syncthreads();   // drains stage vmcnt + orders slot reuse
}

__global__ __launch_bounds__(256, 2) void be_kernel(const float* __restrict__ f,
                                                    float* __restrict__ out) {
    __shared__ float lds[SLICE_F * SLOTS];   // 47616 B
    const int tid = threadIdx.x;

    // bijective XCD chunking; same-XCD blocks share (b, xseg) slab volumes
    int lid = (blockIdx.x & 7) * CPX + (blockIdx.x >> 3);
    int p2i = lid / (NMS * NYT);
    int q2i = lid % (NMS * NYT);
    int b = p2i / NSEG, xseg = p2i % NSEG;
    int ms = q2i / NYT, yt = q2i % NYT;

    const int X0 = 2 + xseg * STEPS;
    const int gy0 = 16 * yt;                 // first staged global y row
    const int core = 4 + 128 * ms;           // first output m of this segment
    const int Gm = core - 8;                 // staged m start (16B-aligned)
    const long long bb = (long long)b * FSZ;

    Ctx ctx;
    ctx.f = f;
    ctx.fbase = f + bb;
    ctx.fend = f + (TOT - 4);
    ctx.tid = tid;
#pragma unroll
    for (int it = 0; it < 3; ++it) {
        int cch = it * 256 + tid;
        int row = cch / ROWU, col = cch - row * ROWU;
        long long o = (long long)(gy0 + row) * SY + Gm + 4 * col;
        if (it == 0) ctx.choff0 = o;
        else if (it == 1) ctx.choff1 = o;
        else ctx.choff2 = o;
    }
    ctx.ch2ok = (512 + tid) < USED_U;

    const int t = tid >> 4;                  // m-tile 0..15
    const int yy = tid & 15;                 // y row within tile
    const int m0 = core + 8 * t;
    const int y = 2 + 16 * yt + yy;

    int jlo = 6 - m0; if (jlo < 0) jlo = 0;  // valid m in [6, 474)
    int jhi = 474 - m0; if (jhi > 8) jhi = 8;
    if (y >= DIM - 2) jhi = -1;              // y edge mask

    // unit of (center row, m0-8); every LDS access is slot-base + rc + imm
    const int rc = (yy + 2) * ROWU + 2 * t;

    // prologue: slabs X0-2..X0+1 -> slots 0..3
    stage_slab(ctx, lds, X0 - 2, 0); stage_slab(ctx, lds, X0 - 1, 1);
    stage_slab(ctx, lds, X0, 2);     stage_slab(ctx, lds, X0 + 1, 3);
    __syncthreads();

    // ring state; seeds = exactly the entries step 0..2 consume at old ages
    F4 CF[4][6], PF[3][4], QF[3][4];
    {
        const float* L2 = lds + 2 * SLICE_F;     // slab X0
        const float* L1 = lds + 1 * SLICE_F;     // slab X0-1
        const float* L0 = lds + 0 * SLICE_F;     // slab X0-2
#pragma unroll
        for (int i = 0; i < 6; ++i) CF[3][i] = LDS4(L2, rc + i);     // C @ s0
#pragma unroll
        for (int i = 1; i < 5; ++i) CF[2][i] = LDS4(L1, rc + i);     // XM @ s0
        CF[1][2] = LDS4(L0, rc + 2); CF[1][3] = LDS4(L0, rc + 3);    // X2M @ s0
#pragma unroll
        for (int i = 0; i < 4; ++i) {
            PF[2][i] = LDS4(L2, rc + ROWU + 1 + i);                  // YP @ s0
            QF[2][i] = LDS4(L2, rc - ROWU + 1 + i);
        }
        PF[1][1] = LDS4(L1, rc + ROWU + 2); PF[1][2] = LDS4(L1, rc + ROWU + 3);
        QF[1][1] = LDS4(L1, rc - ROWU + 2); QF[1][2] = LDS4(L1, rc - ROWU + 3);
    }
    __syncthreads();                 // seeds done before slot 0 reuse
    stage_slab(ctx, lds, X0 + 2, 0); // slab X0+2 -> slot 0 (over X0-2)
    __syncthreads();                 // landed before step 0 reads it

    float e = 0.0f;                  // raw energy (x16 scale)

    // 26 steps = 2 x 12 phases + epilogue phases 0,1 (12 = lcm(4,3) so ring
    // and slot indices depend only on the phase)
    for (int it2 = 0; it2 < 2; ++it2) {
        int xb = X0 + it2 * 12;
        do_step<0>(ctx, lds, xb + 0, rc, jlo, jhi, e, CF, PF, QF, true);
        do_step<1>(ctx, lds, xb + 1, rc, jlo, jhi, e, CF, PF, QF, true);
        do_step<2>(ctx, lds, xb + 2, rc, jlo, jhi, e, CF, PF, QF, true);
        do_step<3>(ctx, lds, xb + 3, rc, jlo, jhi, e, CF, PF, QF, true);
        do_step<4>(ctx, lds, xb + 4, rc, jlo, jhi, e, CF, PF, QF, true);
        do_step<5>(ctx, lds, xb + 5, rc, jlo, jhi, e, CF, PF, QF, true);
        do_step<6>(ctx, lds, xb + 6, rc, jlo, jhi, e, CF, PF, QF, true);
        do_step<7>(ctx, lds, xb + 7, rc, jlo, jhi, e, CF, PF, QF, true);
        do_step<8>(ctx, lds, xb + 8, rc, jlo, jhi, e, CF, PF, QF, true);
        do_step<9>(ctx, lds, xb + 9, rc, jlo, jhi, e, CF, PF, QF, true);
        do_step<10>(ctx, lds, xb + 10, rc, jlo, jhi, e, CF, PF, QF, true);
        do_step<11>(ctx, lds, xb + 11, rc, jlo, jhi, e, CF, PF, QF, true);
    }
    do_step<0>(ctx, lds, X0 + 24, rc, jlo, jhi, e, CF, PF, QF, true);
    do_step<1>(ctx, lds, X0 + 25, rc, jlo, jhi, e, CF, PF, QF, false);

    // wave reduce -> block reduce -> one atomic per block
#pragma unroll
    for (int off = 32; off > 0; off >>= 1) e += __shfl_down(e, off, 64);

    __shared__ float ws[4];
    int lane = tid & 63;
    int wid = tid >> 6;
    if (lane == 0) ws[wid] = e;
    __syncthreads();
    if (tid == 0) {
        // 0.0625 = (0.25)^2 from the two central-difference factors
        const float inv_count = 0.0625f / (156.0f * 156.0f * 156.0f * 3.0f);
        atomicAdd(&out[b], (ws[0] + ws[1] + ws[2] + ws[3]) * inv_count);
    }
}

extern "C" void kernel_launch(void* const* d_in, const int* in_sizes, int n_in,
                              void* d_out, int out_size, void* d_ws, size_t ws_size,
                              hipStream_t stream) {
    const float* f = (const float*)d_in[0];
    float* out = (float*)d_out;

    hipMemsetAsync(d_out, 0, out_size * sizeof(float), stream);

    be_kernel<<<dim3(NBLK), dim3(256), 0, stream>>>(f, out);
}